// Round 1
// baseline (436.969 us; speedup 1.0000x reference)
//
#include <hip/hip_runtime.h>

// EMA: y[b,c,t] = g*y[b,c,t-1] + (1-g)*x[b,c,t],  y[-1]=0, g = weight[c]
// Shapes: B=8, C=512, T=16384 (fp32).  4096 independent rows of length 16384.
//
// One block (256 thr = 4 waves) per row. Each iteration processes a
// contiguous window of 1024 elems (float4/lane, coalesced). Exact parallel
// scan: per-lane 4-elem local scan -> Kogge-Stone wave scan of carries with
// uniform factor g^4 per segment -> LDS cross-wave combine (4 values) ->
// register cross-iteration carry (factor g^1024).

#define B_ 8
#define C_ 512
#define T_ 16384
#define WIN 1024            // elements per iteration window (256 thr * 4)
#define NITER (T_ / WIN)    // 16

__global__ __launch_bounds__(256)
void ema_scan_kernel(const float* __restrict__ x,
                     const float* __restrict__ weight,
                     float* __restrict__ out) {
    __shared__ float lds[8];                 // double-buffered 4 wave-carries

    const int row  = blockIdx.x;             // 0..4095  (b*C + c)
    const int c    = row & (C_ - 1);
    const int tid  = threadIdx.x;
    const int lane = tid & 63;
    const int w    = tid >> 6;               // wave id 0..3

    const float g     = weight[c];
    const float onemg = 1.0f - g;

    // powers of g
    const float g2 = g * g;
    const float g4 = g2 * g2;
    float f[6];                               // f[k] = g^(4*2^k)
    f[0] = g4;
    #pragma unroll
    for (int k = 1; k < 6; ++k) f[k] = f[k - 1] * f[k - 1];
    // lane_factor = g^(4*lane) via binary expansion
    float lane_factor = 1.0f;
    #pragma unroll
    for (int k = 0; k < 6; ++k)
        if (lane & (1 << k)) lane_factor *= f[k];
    const float g256   = f[5] * f[5];
    const float g256sq = g256 * g256;
    const float g1024  = g256sq * g256sq;
    const float g256w  = (w == 0) ? 1.0f
                       : (w == 1) ? g256
                       : (w == 2) ? g256sq
                                  : g256sq * g256;

    const float4* __restrict__ xrow = (const float4*)(x   + (size_t)row * T_);
    float4*       __restrict__ orow = (float4*)      (out + (size_t)row * T_);

    float C = 0.0f;   // y value just before the current window

    for (int it = 0; it < NITER; ++it) {
        const int vidx = it * 256 + tid;      // float4 index within row
        const float4 X = xrow[vidx];

        // local 4-element scan (zero carry-in)
        const float z0 = onemg * X.x;
        const float z1 = fmaf(g, z0, onemg * X.y);
        const float z2 = fmaf(g, z1, onemg * X.z);
        const float z3 = fmaf(g, z2, onemg * X.w);

        // Kogge-Stone inclusive scan of per-lane carries across the wave:
        // v_l = sum_{m<=l} (g^4)^(l-m) * z3_m
        float v = z3;
        #pragma unroll
        for (int k = 0; k < 6; ++k) {
            const float t = __shfl_up(v, 1 << k, 64);
            if (lane >= (1 << k)) v = fmaf(f[k], t, v);
        }
        // exclusive value: y at end of previous lane's chunk (wave-relative)
        float e = __shfl_up(v, 1, 64);
        if (lane == 0) e = 0.0f;

        // cross-wave combine via LDS (double-buffered slots, 1 barrier/iter)
        const int slot = (it & 1) * 4;
        if (lane == 63) lds[slot + w] = v;
        __syncthreads();
        const float s0 = lds[slot + 0], s1 = lds[slot + 1];
        const float s2 = lds[slot + 2], s3 = lds[slot + 3];
        const float t01  = fmaf(g256, s0, s1);
        const float t012 = fmaf(g256, t01, s2);
        const float E    = fmaf(g256, t012, s3);   // window-end value (zero init)
        float W;                                   // wave-start carry (window-rel.)
        if      (w == 0) W = 0.0f;
        else if (w == 1) W = s0;
        else if (w == 2) W = t01;
        else             W = t012;

        // absolute carry just before this thread's 4 elements
        const float cth = fmaf(lane_factor, fmaf(g256w, C, W), e);

        float gp = g * cth;
        float4 Y;
        Y.x = z0 + gp; gp *= g;
        Y.y = z1 + gp; gp *= g;
        Y.z = z2 + gp; gp *= g;
        Y.w = z3 + gp;
        orow[vidx] = Y;

        C = fmaf(g1024, C, E);   // exact cross-window carry
    }
}

extern "C" void kernel_launch(void* const* d_in, const int* in_sizes, int n_in,
                              void* d_out, int out_size, void* d_ws, size_t ws_size,
                              hipStream_t stream) {
    const float* x      = (const float*)d_in[0];
    const float* weight = (const float*)d_in[1];
    float* out          = (float*)d_out;
    ema_scan_kernel<<<B_ * C_, 256, 0, stream>>>(x, weight, out);
}